// Round 7
// baseline (139.383 us; speedup 1.0000x reference)
//
#include <hip/hip_runtime.h>

#define NB     20000
#define NL     320000
#define NOTH   1000
#define BATCH  128
#define ROW    (2*NB + NOTH)   // 41000
#define CAP    80              // events/bus capacity; degree ~ Poisson(32)
#define PAD    16              // ints per counter (64-B line): kills line-level
                               // serialization of the value-returning atomics
#define RPB    4               // batch rows per block (bf16 LDS = 160000 B)
#define NGRP   (BATCH/RPB)     // 32 row-groups
#define BCHUNK 8               // bus chunks (delta)
#define CB     (NB/BCHUNK)     // 2500 buses per block
#define NSLICE 8               // line slices (flows)
#define LPS    (NL/NSLICE)     // 40000 lines per slice

typedef float vf4 __attribute__((ext_vector_type(4)));  // nontemporal-storable

__device__ __forceinline__ float fast_rcp(float a)
{
    float r;
    asm volatile("v_rcp_f32 %0, %1" : "=v"(r) : "v"(a));
    return r;
}
__device__ __forceinline__ float bf2f(ushort u)
{
    union { uint i; float f; } c; c.i = ((uint)u) << 16; return c.f;
}
__device__ __forceinline__ ushort f2bf(float f)
{
    union { uint i; float f; } c; c.f = f; return (ushort)((c.i + 0x8000u) >> 16);
}

// ---------------------------------------------------------------------------
// Kernel 0: zero the padded counters (1.28 MB).
// ---------------------------------------------------------------------------
__global__ __launch_bounds__(256) void zero_k(int* __restrict__ cnt)
{
    const int i = blockIdx.x * 256 + threadIdx.x;      // int4 index
    if (i < NB * PAD / 4) ((int4*)cnt)[i] = make_int4(0, 0, 0, 0);
}

// ---------------------------------------------------------------------------
// Kernel 1 (batch-independent): build capacity-padded CSR by bus.
// Event word: bits31:17 = other endpoint, bit16 = side (B=='to' -> -h),
// bits15:0 = bf16(reactance*limit). Counters padded to 1/cacheline.
// ---------------------------------------------------------------------------
__global__ __launch_bounds__(256) void build_k(
    const int* __restrict__ fidx, const int* __restrict__ tidx,
    const float* __restrict__ xr, const float* __restrict__ lim,
    int* __restrict__ cnt, unsigned* __restrict__ bins)
{
    const int q = blockIdx.x * 256 + threadIdx.x;      // int4 index over lines
    if (q >= NL / 4) return;
    const int4   f = ((const int4*)fidx)[q];
    const int4   t = ((const int4*)tidx)[q];
    const float4 r = ((const float4*)xr)[q];
    const float4 L = ((const float4*)lim)[q];

    #define EMIT(FI, TI, RC, LC)                                             \
    {                                                                        \
        union { float f; unsigned u; } c; c.f = (RC) * (LC);                 \
        const unsigned rl16 = (c.u + 0x8000u) >> 16;                         \
        const int p0 = atomicAdd(&cnt[(FI) * PAD], 1);                       \
        if (p0 < CAP) bins[(size_t)p0 * NB + (FI)] =                         \
            ((unsigned)(TI) << 17) | rl16;                                   \
        const int p1 = atomicAdd(&cnt[(TI) * PAD], 1);                       \
        if (p1 < CAP) bins[(size_t)p1 * NB + (TI)] =                         \
            ((unsigned)(FI) << 17) | (1u << 16) | rl16;                      \
    }
    EMIT(f.x, t.x, r.x, L.x)
    EMIT(f.y, t.y, r.y, L.y)
    EMIT(f.z, t.z, r.z, L.z)
    EMIT(f.w, t.w, r.w, L.w)
    #undef EMIT
}

// ---------------------------------------------------------------------------
// Kernel 2: atomic-free delta + output assembly, 4 batch rows per block.
// LDS: 4 angle rows as bf16 (160000 B). Each event word read ONCE serves all
// 4 rows (bins logical traffic /4). Output base angle re-read f32 from x.
// ---------------------------------------------------------------------------
__global__ __launch_bounds__(1024) void delta_copy_k(
    const float* __restrict__ x, const int* __restrict__ cnt,
    const unsigned* __restrict__ bins, float* __restrict__ out)
{
    extern __shared__ ushort a4[];                    // [RPB][NB] bf16
    const int g  = blockIdx.x % NGRP;                 // row-group: rows 4g..4g+3
    const int cb = blockIdx.x / NGRP;                 // bus chunk
    const int row0 = g * RPB;

    // stage 4 angle rows f32->bf16 (float4 reads, ushort4 LDS writes)
    for (int i = threadIdx.x; i < RPB * (NB / 4); i += 1024) {
        const int r = i / (NB / 4), j = i % (NB / 4);
        const float4 v = ((const float4*)(x + (size_t)(row0 + r) * ROW + NB))[j];
        ushort4 u;
        u.x = f2bf(v.x); u.y = f2bf(v.y); u.z = f2bf(v.z); u.w = f2bf(v.w);
        ((ushort4*)a4)[i] = u;
    }
    __syncthreads();

    // copy voltages slice (+ other_params on chunk 0) for the 4 rows
    for (int r = 0; r < RPB; ++r) {
        const float* __restrict__ xrow = x   + (size_t)(row0 + r) * ROW;
        float*       __restrict__ orow = out + (size_t)(row0 + r) * ROW;
        for (int i = threadIdx.x; i < CB / 4; i += 1024)
            ((float4*)(orow + cb * CB))[i] = ((const float4*)(xrow + cb * CB))[i];
        if (cb == 0)
            for (int i = threadIdx.x; i < NOTH / 4; i += 1024)
                ((float4*)(orow + 2 * NB))[i] = ((const float4*)(xrow + 2 * NB))[i];
    }

    const int base = cb * CB;
    for (int bus = base + (int)threadIdx.x; bus < base + CB; bus += 1024) {
        const int n = min(cnt[bus * PAD], CAP);
        float ab[RPB], ds[RPB];
        #pragma unroll
        for (int r = 0; r < RPB; ++r) {
            ab[r] = bf2f(a4[r * NB + bus]);
            ds[r] = 0.0f;
        }
        for (int k = 0; k < n; ++k) {
            const unsigned w  = bins[(size_t)k * NB + bus];
            const int   other = (int)(w >> 17);
            const float rl    = __uint_as_float((w & 0xFFFFu) << 16);
            const float sgn   = (w & (1u << 16)) ? -0.5f : 0.5f;
            #pragma unroll
            for (int r = 0; r < RPB; ++r) {
                const float ad = ab[r] - bf2f(a4[r * NB + other]);
                if (fabsf(ad) > rl)
                    ds[r] += sgn * (copysignf(rl, ad) - ad);
            }
        }
        #pragma unroll
        for (int r = 0; r < RPB; ++r) {
            const size_t o = (size_t)(row0 + r) * ROW + NB + bus;
            out[o] = x[o] + ds[r];                    // f32 base + adjustment
        }
    }
}

// ---------------------------------------------------------------------------
// Kernel 3: flows2, 4 batch rows per block (bf16 LDS staging of angles2),
// 8 line slices. Line data logical reads /4; rcp shared across rows;
// nontemporal float4 stores of the 164 MB output.
// ---------------------------------------------------------------------------
__global__ __launch_bounds__(1024) void flows_lds_k(
    const float* __restrict__ out, const int* __restrict__ fidx,
    const int* __restrict__ tidx, const float* __restrict__ xr,
    float* __restrict__ f2)
{
    extern __shared__ ushort a4[];                    // [RPB][NB] bf16
    const int g = blockIdx.x % NGRP;                  // rows 4g..4g+3
    const int s = blockIdx.x / NGRP;                  // line slice
    const int row0 = g * RPB;

    for (int i = threadIdx.x; i < RPB * (NB / 4); i += 1024) {
        const int r = i / (NB / 4), j = i % (NB / 4);
        const float4 v = ((const float4*)(out + (size_t)(row0 + r) * ROW + NB))[j];
        ushort4 u;
        u.x = f2bf(v.x); u.y = f2bf(v.y); u.z = f2bf(v.z); u.w = f2bf(v.w);
        ((ushort4*)a4)[i] = u;
    }
    __syncthreads();

    const int q0 = s * (LPS / 4);
    const int q1 = q0 + (LPS / 4);
    for (int q = q0 + (int)threadIdx.x; q < q1; q += 1024) {
        const int4   f = ((const int4*)fidx)[q];
        const int4   t = ((const int4*)tidx)[q];
        const float4 r = ((const float4*)xr)[q];
        const float4 ir = make_float4(fast_rcp(r.x), fast_rcp(r.y),
                                      fast_rcp(r.z), fast_rcp(r.w));
        #pragma unroll
        for (int rr = 0; rr < RPB; ++rr) {
            const ushort* __restrict__ a = a4 + rr * NB;
            vf4 o;
            o.x = (bf2f(a[f.x]) - bf2f(a[t.x])) * ir.x;
            o.y = (bf2f(a[f.y]) - bf2f(a[t.y])) * ir.y;
            o.z = (bf2f(a[f.z]) - bf2f(a[t.z])) * ir.z;
            o.w = (bf2f(a[f.w]) - bf2f(a[t.w])) * ir.w;
            __builtin_nontemporal_store(
                o, &((vf4*)(f2 + (size_t)(row0 + rr) * NL))[q]);
        }
    }
}

extern "C" void kernel_launch(void* const* d_in, const int* in_sizes, int n_in,
                              void* d_out, int out_size, void* d_ws, size_t ws_size,
                              hipStream_t stream)
{
    const float* x   = (const float*)d_in[0];
    const int*   fi  = (const int*)  d_in[1];
    const int*   ti  = (const int*)  d_in[2];
    const float* xr  = (const float*)d_in[3];
    const float* lim = (const float*)d_in[4];

    float* out    = (float*)d_out;                      // (128, 41000)
    float* flows2 = out + (size_t)BATCH * ROW;          // (128, 320000)

    int*      cnt  = (int*)d_ws;                        // NB*PAD ints (1.28 MB)
    unsigned* bins = (unsigned*)((char*)d_ws + (size_t)NB * PAD * 4); // 6.4 MB

    zero_k<<<dim3((NB * PAD / 4 + 255) / 256), dim3(256), 0, stream>>>(cnt);

    build_k<<<dim3((NL / 4 + 255) / 256), dim3(256), 0, stream>>>(
        fi, ti, xr, lim, cnt, bins);

    delta_copy_k<<<dim3(BCHUNK * NGRP), dim3(1024),
                   RPB * NB * sizeof(ushort), stream>>>(x, cnt, bins, out);

    flows_lds_k<<<dim3(NSLICE * NGRP), dim3(1024),
                  RPB * NB * sizeof(ushort), stream>>>(out, fi, ti, xr, flows2);
}

// Round 8
// 116.155 us; speedup vs baseline: 1.2000x; 1.2000x over previous
//
#include <hip/hip_runtime.h>

#define NB     20000
#define NL     320000
#define NOTH   1000
#define BATCH  128
#define ROW    (2*NB + NOTH)   // 41000
#define CAP    80              // events/bus capacity; degree ~ Poisson(32), max ~60
#define NBLK   256             // histo/place blocks
#define LSEG   (NL/NBLK)       // 1250 lines per block
#define BCHUNK 8               // bus chunks (delta) — R5-identical
#define CB     (NB/BCHUNK)     // 2500 buses per block
#define NSLICE 2               // line slices (flows) — R5-identical
#define LPS    (NL/NSLICE)     // 160000 lines per slice

__device__ __forceinline__ float fast_rcp(float a)
{
    float r;
    asm volatile("v_rcp_f32 %0, %1" : "=v"(r) : "v"(a));
    return r;
}

// ============================ build path A (atomic-free) ====================
// histo_k: per-block LDS histogram of a 1250-line segment -> ushort partials.
__global__ __launch_bounds__(512) void histo_k(
    const int* __restrict__ fidx, const int* __restrict__ tidx,
    ushort* __restrict__ H)
{
    extern __shared__ uint h[];                       // NB uints = 80 KB
    for (int i = threadIdx.x; i < NB; i += 512) h[i] = 0u;
    __syncthreads();

    const int l0 = blockIdx.x * LSEG;
    for (int l = l0 + (int)threadIdx.x; l < l0 + LSEG; l += 512) {
        atomicAdd(&h[fidx[l]], 1u);                   // LDS atomics, CU-local
        atomicAdd(&h[tidx[l]], 1u);
    }
    __syncthreads();

    ushort* __restrict__ Hrow = H + (size_t)blockIdx.x * NB;
    for (int i = threadIdx.x; i < NB / 2; i += 512) {
        ushort2 u; u.x = (ushort)h[2 * i]; u.y = (ushort)h[2 * i + 1];
        ((ushort2*)Hrow)[i] = u;
    }
}

// scan_k: per-bus exclusive prefix over the 256 block partials, IN PLACE.
// Wave-coalesced: lanes u..u+63 read/write contiguous ushorts at each b.
__global__ __launch_bounds__(512) void scan_k(
    ushort* __restrict__ H, int* __restrict__ cnt)
{
    const int u = blockIdx.x * 512 + threadIdx.x;
    if (u >= NB) return;
    uint run = 0;
    for (int b = 0; b < NBLK; ++b) {
        const uint v = H[(size_t)b * NB + u];
        H[(size_t)b * NB + u] = (ushort)run;          // exclusive prefix
        run += v;
    }
    cnt[u] = (int)run;
}

// place_k: slot = global prefix (staged 40-KB row in LDS) + local LDS rank.
// Event word: bits31:17 = other endpoint, bit16 = side, bits15:0 = bf16(rl).
__global__ __launch_bounds__(512) void place_k(
    const int* __restrict__ fidx, const int* __restrict__ tidx,
    const float* __restrict__ xr, const float* __restrict__ lim,
    const ushort* __restrict__ H, unsigned* __restrict__ bins)
{
    extern __shared__ char sm[];
    uint*   __restrict__ h    = (uint*)sm;            // NB uints = 80 KB
    ushort* __restrict__ pref = (ushort*)(sm + NB * 4); // NB ushort = 40 KB

    const ushort* __restrict__ Hrow = H + (size_t)blockIdx.x * NB;
    for (int i = threadIdx.x; i < NB; i += 512) h[i] = 0u;
    for (int i = threadIdx.x; i < NB / 2; i += 512)
        ((ushort2*)pref)[i] = ((const ushort2*)Hrow)[i];
    __syncthreads();

    const int l0 = blockIdx.x * LSEG;
    for (int l = l0 + (int)threadIdx.x; l < l0 + LSEG; l += 512) {
        const int fi = fidx[l];
        const int ti = tidx[l];
        union { float f; unsigned u; } c; c.f = xr[l] * lim[l];
        const unsigned rl16 = (c.u + 0x8000u) >> 16;

        const uint s0 = (uint)pref[fi] + atomicAdd(&h[fi], 1u);
        if (s0 < CAP) bins[(size_t)s0 * NB + fi] = ((unsigned)ti << 17) | rl16;
        const uint s1 = (uint)pref[ti] + atomicAdd(&h[ti], 1u);
        if (s1 < CAP) bins[(size_t)s1 * NB + ti] =
            ((unsigned)fi << 17) | (1u << 16) | rl16;
    }
}

// ============================ build path B (fallback, R5) ===================
__global__ __launch_bounds__(256) void zero_k(int* __restrict__ cnt)
{
    const int i = blockIdx.x * 256 + threadIdx.x;
    if (i < NB / 4) ((int4*)cnt)[i] = make_int4(0, 0, 0, 0);
}

__global__ __launch_bounds__(256) void build_k(
    const int* __restrict__ fidx, const int* __restrict__ tidx,
    const float* __restrict__ xr, const float* __restrict__ lim,
    int* __restrict__ cnt, unsigned* __restrict__ bins)
{
    const int q = blockIdx.x * 256 + threadIdx.x;
    if (q >= NL / 4) return;
    const int4   f = ((const int4*)fidx)[q];
    const int4   t = ((const int4*)tidx)[q];
    const float4 r = ((const float4*)xr)[q];
    const float4 L = ((const float4*)lim)[q];
    #define EMIT(FI, TI, RC, LC)                                             \
    {                                                                        \
        union { float f; unsigned u; } c; c.f = (RC) * (LC);                 \
        const unsigned rl16 = (c.u + 0x8000u) >> 16;                         \
        const int p0 = atomicAdd(&cnt[FI], 1);                               \
        if (p0 < CAP) bins[(size_t)p0 * NB + (FI)] =                         \
            ((unsigned)(TI) << 17) | rl16;                                   \
        const int p1 = atomicAdd(&cnt[TI], 1);                               \
        if (p1 < CAP) bins[(size_t)p1 * NB + (TI)] =                         \
            ((unsigned)(FI) << 17) | (1u << 16) | rl16;                      \
    }
    EMIT(f.x, t.x, r.x, L.x)
    EMIT(f.y, t.y, r.y, L.y)
    EMIT(f.z, t.z, r.z, L.z)
    EMIT(f.w, t.w, r.w, L.w)
    #undef EMIT
}

// ============================ delta + flows (R5-identical) ==================
__global__ __launch_bounds__(1024) void delta_copy_k(
    const float* __restrict__ x, const int* __restrict__ cnt,
    const unsigned* __restrict__ bins, float* __restrict__ out)
{
    extern __shared__ float a[];                      // NB f32 = 80 KB
    const int b  = blockIdx.x % BATCH;                // XCD = b%8
    const int cb = blockIdx.x / BATCH;

    const float* __restrict__ xrow = x   + (size_t)b * ROW;
    float*       __restrict__ orow = out + (size_t)b * ROW;

    for (int i = threadIdx.x; i < NB / 4; i += 1024)
        ((float4*)a)[i] = ((const float4*)(xrow + NB))[i];
    __syncthreads();

    for (int i = threadIdx.x; i < CB / 4; i += 1024)
        ((float4*)(orow + cb * CB))[i] = ((const float4*)(xrow + cb * CB))[i];
    if (cb == 0)
        for (int i = threadIdx.x; i < NOTH / 4; i += 1024)
            ((float4*)(orow + 2 * NB))[i] = ((const float4*)(xrow + 2 * NB))[i];

    const int base = cb * CB;
    for (int bus = base + (int)threadIdx.x; bus < base + CB; bus += 1024) {
        const int   n  = min(cnt[bus], CAP);
        const float ab = a[bus];
        float ds = 0.0f;
        int k = 0;
        #define CONTRIB(W)                                                   \
        {                                                                    \
            const unsigned w  = (W);                                         \
            const int   other = (int)(w >> 17);                              \
            const float rl    = __uint_as_float((w & 0xFFFFu) << 16);        \
            const float ad    = ab - a[other];                               \
            if (fabsf(ad) > rl) {                                            \
                float hh = 0.5f * (copysignf(rl, ad) - ad);                  \
                if (w & (1u << 16)) hh = -hh;                                \
                ds += hh;                                                    \
            }                                                                \
        }
        for (; k + 4 <= n; k += 4) {
            const unsigned w0 = bins[(size_t)(k + 0) * NB + bus];
            const unsigned w1 = bins[(size_t)(k + 1) * NB + bus];
            const unsigned w2 = bins[(size_t)(k + 2) * NB + bus];
            const unsigned w3 = bins[(size_t)(k + 3) * NB + bus];
            CONTRIB(w0) CONTRIB(w1) CONTRIB(w2) CONTRIB(w3)
        }
        for (; k < n; ++k) CONTRIB(bins[(size_t)k * NB + bus])
        #undef CONTRIB
        orow[NB + bus] = ab + ds;
    }
}

__global__ __launch_bounds__(1024) void flows_lds_k(
    const float* __restrict__ out, const int* __restrict__ fidx,
    const int* __restrict__ tidx, const float* __restrict__ xr,
    float* __restrict__ f2)
{
    extern __shared__ float a2[];                     // NB f32 = 80 KB
    const int b = blockIdx.x % BATCH;
    const int s = blockIdx.x / BATCH;

    const float* __restrict__ src = out + (size_t)b * ROW + NB;
    for (int i = threadIdx.x; i < NB / 4; i += 1024)
        ((float4*)a2)[i] = ((const float4*)src)[i];
    __syncthreads();

    float* __restrict__ frow = f2 + (size_t)b * NL;
    const int q0 = s * (LPS / 4);
    const int q1 = q0 + (LPS / 4);
    for (int q = q0 + (int)threadIdx.x; q < q1; q += 1024) {
        const int4   f = ((const int4*)fidx)[q];
        const int4   t = ((const int4*)tidx)[q];
        const float4 r = ((const float4*)xr)[q];
        float4 o;
        o.x = (a2[f.x] - a2[t.x]) * fast_rcp(r.x);
        o.y = (a2[f.y] - a2[t.y]) * fast_rcp(r.y);
        o.z = (a2[f.z] - a2[t.z]) * fast_rcp(r.z);
        o.w = (a2[f.w] - a2[t.w]) * fast_rcp(r.w);
        ((float4*)frow)[q] = o;
    }
}

extern "C" void kernel_launch(void* const* d_in, const int* in_sizes, int n_in,
                              void* d_out, int out_size, void* d_ws, size_t ws_size,
                              hipStream_t stream)
{
    const float* x   = (const float*)d_in[0];
    const int*   fi  = (const int*)  d_in[1];
    const int*   ti  = (const int*)  d_in[2];
    const float* xr  = (const float*)d_in[3];
    const float* lim = (const float*)d_in[4];

    float* out    = (float*)d_out;                      // (128, 41000)
    float* flows2 = out + (size_t)BATCH * ROW;          // (128, 320000)

    const size_t hBytes = (size_t)NBLK * NB * sizeof(ushort);   // 10.24 MB
    const size_t needed = hBytes + (size_t)NB * 4 + (size_t)CAP * NB * 4;

    int* cnt;
    unsigned* bins;

    if (ws_size >= needed) {
        // ---- atomic-free build: histo -> scan -> place ----
        ushort* H = (ushort*)d_ws;
        cnt  = (int*)((char*)d_ws + hBytes);
        bins = (unsigned*)((char*)d_ws + hBytes + (size_t)NB * 4);

        histo_k<<<dim3(NBLK), dim3(512), NB * sizeof(uint), stream>>>(fi, ti, H);
        scan_k<<<dim3((NB + 511) / 512), dim3(512), 0, stream>>>(H, cnt);
        place_k<<<dim3(NBLK), dim3(512),
                  NB * sizeof(uint) + NB * sizeof(ushort), stream>>>(
            fi, ti, xr, lim, H, bins);
    } else {
        // ---- fallback: R5 atomic build ----
        cnt  = (int*)d_ws;
        bins = (unsigned*)((char*)d_ws + (size_t)NB * 4);
        zero_k<<<dim3((NB / 4 + 255) / 256), dim3(256), 0, stream>>>(cnt);
        build_k<<<dim3((NL / 4 + 255) / 256), dim3(256), 0, stream>>>(
            fi, ti, xr, lim, cnt, bins);
    }

    delta_copy_k<<<dim3(BCHUNK * BATCH), dim3(1024), NB * sizeof(float), stream>>>(
        x, cnt, bins, out);

    flows_lds_k<<<dim3(NSLICE * BATCH), dim3(1024), NB * sizeof(float), stream>>>(
        out, fi, ti, xr, flows2);
}